// Round 5
// baseline (1910.972 us; speedup 1.0000x reference)
//
#include <hip/hip_runtime.h>
#include <stdint.h>
#include <stddef.h>

// EfficientAttention: B=4, L=4096, D=1024, H=16, hd=64. Inputs fp32.
// X split to bf16 hi+lo (2-term MFMA); W rounded to bf16 (lo term ~0 at 1/32 scale).
// attn_mix uses associativity: out = (smQ·sK)·V with M=smQ·sK only 16x16.
// ws: Wh 6MB + Xh/Xl 32MB + Y 48MB = 86 MB, chunked over 2x8192 tokens.
#define TOKENS 16384
#define CHUNK  8192
#define DMODEL 1024

typedef short   short8 __attribute__((ext_vector_type(8)));
typedef __bf16  bfx8   __attribute__((ext_vector_type(8)));
typedef float   f32x4  __attribute__((ext_vector_type(4)));
typedef unsigned short ushort_t;
typedef unsigned short us4 __attribute__((ext_vector_type(4)));

__device__ inline float bf2f(ushort_t u) {
  union { unsigned int i; float f; } x; x.i = ((unsigned int)u) << 16; return x.f;
}
__device__ inline ushort_t f2bf(float f) {
  union { float f; unsigned int i; } x; x.f = f;
  unsigned int r = x.i + 0x7fff + ((x.i >> 16) & 1);
  return (ushort_t)(r >> 16);
}

// ---- MFMA wrapper: dual-signature hedge (short8 vs v8bf16 builtin arg) ----
template <typename V>
__device__ auto mfma16_(V a, V b, f32x4 c, int)
    -> decltype(__builtin_amdgcn_mfma_f32_16x16x32_bf16(a, b, c, 0, 0, 0)) {
  return __builtin_amdgcn_mfma_f32_16x16x32_bf16(a, b, c, 0, 0, 0);
}
template <typename V>
__device__ f32x4 mfma16_(V a, V b, f32x4 c, long) {
  return __builtin_amdgcn_mfma_f32_16x16x32_bf16(
      __builtin_bit_cast(bfx8, a), __builtin_bit_cast(bfx8, b), c, 0, 0, 0);
}
__device__ inline f32x4 MFMA16(short8 a, short8 b, f32x4 c) {
  return mfma16_(a, b, c, 0);
}

__device__ inline void gload_lds16(const void* g, void* l) {
  __builtin_amdgcn_global_load_lds(
      (const __attribute__((address_space(1))) unsigned int*)g,
      (__attribute__((address_space(3))) unsigned int*)l, 16, 0, 0);
}

// ---- W -> bf16 (hi only), all three weights in one launch ----
__global__ __launch_bounds__(256) void conv_w(
    const float* __restrict__ Wq, const float* __restrict__ Wk,
    const float* __restrict__ Wv, ushort_t* __restrict__ Wh, int n4)
{
  int i = blockIdx.x * 256 + threadIdx.x;
  if (i >= n4) return;
  const float* src = (blockIdx.y == 0) ? Wq : ((blockIdx.y == 1) ? Wk : Wv);
  f32x4 x = ((const f32x4*)src)[i];
  us4 h;
  #pragma unroll
  for (int j = 0; j < 4; ++j) h[j] = f2bf(x[j]);
  ((us4*)(Wh + (size_t)blockIdx.y * DMODEL * DMODEL))[i] = h;
}

// ---- X -> bf16 hi + lo ----
__global__ __launch_bounds__(256) void split_x(
    const float* __restrict__ src, ushort_t* __restrict__ hi,
    ushort_t* __restrict__ lo, int n4)
{
  int i = blockIdx.x * 256 + threadIdx.x;
  if (i >= n4) return;
  f32x4 x = ((const f32x4*)src)[i];
  us4 h, l;
  #pragma unroll
  for (int j = 0; j < 4; ++j) {
    ushort_t hh = f2bf(x[j]);
    h[j] = hh;
    l[j] = f2bf(x[j] - bf2f(hh));
  }
  ((us4*)hi)[i] = h;
  ((us4*)lo)[i] = l;
}

// ---------------- GEMM: Y[z] = Xc @ W[z]^T, 2-term split ----------------
// 128x128 tile, BK=32, 256 threads (4 waves, 2x2, 64x64/wave), m97 pattern.
// LDS 24 KB, VGPR 60 -> 6 blocks/CU at (256,6); grid 1536 = exactly 6/CU.
__global__ __launch_bounds__(256, 6) void gemm2(
    const ushort_t* __restrict__ Xh, const ushort_t* __restrict__ Xl,
    const ushort_t* __restrict__ Wh, ushort_t* __restrict__ Y)
{
  __shared__ ushort_t Ah[128 * 32];  // 8 KB each, row-major stride 32
  __shared__ ushort_t Al[128 * 32];
  __shared__ ushort_t Bh[128 * 32];

  const int tid  = threadIdx.x;
  const int lane = tid & 63;
  const int wave = tid >> 6;
  const int quad = lane >> 4;
  const int l15  = lane & 15;
  const int wm   = wave & 1, wn = wave >> 1;

  const int m0 = blockIdx.x * 128;
  const int n0 = blockIdx.y * 128;
  const int z  = blockIdx.z;

  const ushort_t* Agh = Xh + (size_t)m0 * DMODEL;
  const ushort_t* Agl = Xl + (size_t)m0 * DMODEL;
  const ushort_t* Bgh = Wh + (size_t)z * DMODEL * DMODEL + (size_t)n0 * DMODEL;
  ushort_t* Yp = Y + (size_t)z * CHUNK * DMODEL;

  // staging: chunk c = p*256 + tid (16B = 8 bf16); row = c>>2, koff = (c&3)*8
  const int s_row = tid >> 2;
  const int s_off = (tid & 3) * 8;

  f32x4 acc[4][4] = {};

  const short8* Ahv = (const short8*)Ah;  // index = row*4 + k/8
  const short8* Alv = (const short8*)Al;
  const short8* Bhv = (const short8*)Bh;

  for (int k0 = 0; k0 < DMODEL; k0 += 32) {
    #pragma unroll
    for (int p = 0; p < 2; ++p) {
      size_t g = (size_t)(p * 64 + s_row) * DMODEL + k0 + s_off;
      int ldso = (p * 256 + wave * 64) * 16;
      gload_lds16(Agh + g, (char*)Ah + ldso);
      gload_lds16(Agl + g, (char*)Al + ldso);
      gload_lds16(Bgh + g, (char*)Bh + ldso);
    }
    __syncthreads();  // compiler drains vmcnt(0) before barrier

    short8 ah[4], al[4], bh[4];
    #pragma unroll
    for (int i = 0; i < 4; ++i) {
      int idx = (wm * 64 + i * 16 + l15) * 4 + quad;  // A[m=lane&15][k=quad*8+j]
      ah[i] = Ahv[idx];
      al[i] = Alv[idx];
    }
    #pragma unroll
    for (int j = 0; j < 4; ++j)
      bh[j] = Bhv[(wn * 64 + j * 16 + l15) * 4 + quad]; // B[k][n] = W[n][k]

    #pragma unroll
    for (int i = 0; i < 4; ++i) {
      #pragma unroll
      for (int j = 0; j < 4; ++j) {
        acc[i][j] = MFMA16(ah[i], bh[j], acc[i][j]);
        acc[i][j] = MFMA16(al[i], bh[j], acc[i][j]);
      }
    }
    __syncthreads();
  }

  // C/D layout: col = lane&15, row = quad*4 + reg
  #pragma unroll
  for (int i = 0; i < 4; ++i) {
    #pragma unroll
    for (int j = 0; j < 4; ++j) {
      #pragma unroll
      for (int r = 0; r < 4; ++r) {
        int row = m0 + wm * 64 + i * 16 + quad * 4 + r;
        int col = n0 + wn * 64 + j * 16 + l15;
        Yp[(size_t)row * DMODEL + col] = f2bf(acc[i][j][r]);
      }
    }
  }
}

// ---------------- Phase 2: per-token mixing (1 wave/token) ----------------
// out = (smQ . sK) . V ; M = smQ.sK is 16x16 -> 4x fewer LDS reads + FMAs
// than materializing tran_V (64x64).
__global__ __launch_bounds__(256) void attn_mix(
    const ushort_t* __restrict__ QKV, float* __restrict__ Out)
{
  // per-wave regions; stride 68 floats (272B, 16B-aligned, breaks bank stride)
  __shared__ float sqT_s[4][16 * 68];
  __shared__ float skT_s[4][16 * 68];
  __shared__ float M_s[4][256];

  const int tid  = threadIdx.x;
  const int lane = tid & 63;
  const int wv   = tid >> 6;
  const int tok  = blockIdx.x * 4 + wv;

  float* sqT = sqT_s[wv];
  float* skT = skT_s[wv];
  float* M   = M_s[wv];

  const size_t base = (size_t)tok * DMODEL;
  const ushort_t* Qg = QKV + base;
  const ushort_t* Kg = QKV + (size_t)CHUNK * DMODEL + base;
  const ushort_t* Vg = QKV + 2 * (size_t)CHUNK * DMODEL + base;

  float q[16], k[16], v[16];
  #pragma unroll
  for (int h = 0; h < 16; ++h) {
    q[h] = bf2f(Qg[h * 64 + lane]);
    k[h] = bf2f(Kg[h * 64 + lane]);
    v[h] = bf2f(Vg[h * 64 + lane]);
  }

  // sK[d=lane][h] = softmax over h of K[h][d]  (per-lane)
  float mx = k[0];
  #pragma unroll
  for (int h = 1; h < 16; ++h) mx = fmaxf(mx, k[h]);
  float ssum = 0.f;
  #pragma unroll
  for (int h = 0; h < 16; ++h) { k[h] = __expf(k[h] - mx); ssum += k[h]; }
  float inv = 1.f / ssum;
  #pragma unroll
  for (int h = 0; h < 16; ++h) skT[h * 68 + lane] = k[h] * inv;  // skT[h'][d]

  // smQ[h][d=lane] = softmax over d of Q[h][d]  (wave reductions)
  #pragma unroll
  for (int h = 0; h < 16; ++h) {
    float m = q[h];
    for (int off = 32; off; off >>= 1) m = fmaxf(m, __shfl_xor(m, off));
    float e = __expf(q[h] - m);
    float s2 = e;
    for (int off = 32; off; off >>= 1) s2 += __shfl_xor(s2, off);
    sqT[h * 68 + lane] = e / s2;                                 // sqT[h][d]
  }

  __syncthreads();

  // M[h][h'] = sum_d sqT[h][d] * skT[h'][d]; lane -> h=lane>>2, h'=(lane&3)*4+p
  {
    const int hm = lane >> 2;
    const int hp = (lane & 3) * 4;
    const f32x4* sqrow = (const f32x4*)(sqT + hm * 68);
    f32x4 m4;
    #pragma unroll
    for (int p = 0; p < 4; ++p) {
      const f32x4* skrow = (const f32x4*)(skT + (hp + p) * 68);
      float dot = 0.f;
      #pragma unroll
      for (int j = 0; j < 16; ++j) {
        f32x4 a = sqrow[j], b = skrow[j];
        dot += a[0] * b[0] + a[1] * b[1] + a[2] * b[2] + a[3] * b[3];
      }
      m4[p] = dot;
    }
    *((f32x4*)(M + hm * 16 + hp)) = m4;
  }

  __syncthreads();

  // out[h][e=lane] = sum_h' M[h][h'] * V[h'][e]  (M broadcast, v in regs)
  #pragma unroll
  for (int h = 0; h < 16; ++h) {
    const f32x4* mr = (const f32x4*)(M + h * 16);
    float o = 0.f;
    #pragma unroll
    for (int j = 0; j < 4; ++j) {
      f32x4 w = mr[j];
      o += w[0] * v[j * 4] + w[1] * v[j * 4 + 1] + w[2] * v[j * 4 + 2] + w[3] * v[j * 4 + 3];
    }
    Out[base + h * 64 + lane] = o;
  }
}

extern "C" void kernel_launch(void* const* d_in, const int* in_sizes, int n_in,
                              void* d_out, int out_size, void* d_ws, size_t ws_size,
                              hipStream_t stream) {
  const float* X  = (const float*)d_in[0];
  const float* Wq = (const float*)d_in[1];
  const float* Wk = (const float*)d_in[2];
  const float* Wv = (const float*)d_in[3];
  float* Out = (float*)d_out;

  // ws layout (ushort elems): Wh[3M] Xh[8M] Xl[8M] Y[24M] = 86 MB
  const size_t WSZ = (size_t)DMODEL * DMODEL;
  const size_t XSZ = (size_t)CHUNK * DMODEL;
  ushort_t* Wh = (ushort_t*)d_ws;
  ushort_t* Xh = Wh + 3 * WSZ;
  ushort_t* Xl = Xh + XSZ;
  ushort_t* Y  = Xl + XSZ;

  const int wn4 = (int)(WSZ / 4);
  dim3 gw((wn4 + 255) / 256, 3);
  conv_w<<<gw, 256, 0, stream>>>(Wq, Wk, Wv, Wh, wn4);

  const int xn4 = (int)(XSZ / 4);
  dim3 gg(CHUNK / 128, DMODEL / 128, 3);
  for (int c = 0; c < 2; ++c) {
    split_x<<<(xn4 + 255) / 256, 256, 0, stream>>>(X + (size_t)c * XSZ, Xh, Xl, xn4);
    gemm2<<<gg, 256, 0, stream>>>(Xh, Xl, Wh, Y);
    attn_mix<<<CHUNK / 4, 256, 0, stream>>>(Y, Out + (size_t)c * XSZ);
  }
}

// Round 6
// 397.844 us; speedup vs baseline: 4.8033x; 4.8033x over previous
//
#include <hip/hip_runtime.h>
#include <stdint.h>
#include <stddef.h>

// EfficientAttention: B=4, L=4096, D=1024, H=16, hd=64. Inputs fp32.
// X split to bf16 hi+lo (2-term MFMA); W rounded to bf16 (lo term ~0 at 1/32 scale).
// attn_mix uses associativity: out = (smQ·sK)·V with M=smQ·sK only 16x16.
// ws: Wh 6MB + Xh/Xl 32MB + Y 48MB = 86 MB, chunked over 2x8192 tokens.
// NOTE R5: __launch_bounds__(256,6) on gemm2 forced VGPR 60->40 and spilled
// accumulators to scratch (FETCH 70MB->1.7GB, 875us). Keep (256,4).
#define TOKENS 16384
#define CHUNK  8192
#define DMODEL 1024

typedef short   short8 __attribute__((ext_vector_type(8)));
typedef __bf16  bfx8   __attribute__((ext_vector_type(8)));
typedef float   f32x4  __attribute__((ext_vector_type(4)));
typedef unsigned short ushort_t;
typedef unsigned short us4 __attribute__((ext_vector_type(4)));

__device__ inline float bf2f(ushort_t u) {
  union { unsigned int i; float f; } x; x.i = ((unsigned int)u) << 16; return x.f;
}
__device__ inline ushort_t f2bf(float f) {
  union { float f; unsigned int i; } x; x.f = f;
  unsigned int r = x.i + 0x7fff + ((x.i >> 16) & 1);
  return (ushort_t)(r >> 16);
}

// ---- MFMA wrapper: dual-signature hedge (short8 vs v8bf16 builtin arg) ----
template <typename V>
__device__ auto mfma16_(V a, V b, f32x4 c, int)
    -> decltype(__builtin_amdgcn_mfma_f32_16x16x32_bf16(a, b, c, 0, 0, 0)) {
  return __builtin_amdgcn_mfma_f32_16x16x32_bf16(a, b, c, 0, 0, 0);
}
template <typename V>
__device__ f32x4 mfma16_(V a, V b, f32x4 c, long) {
  return __builtin_amdgcn_mfma_f32_16x16x32_bf16(
      __builtin_bit_cast(bfx8, a), __builtin_bit_cast(bfx8, b), c, 0, 0, 0);
}
__device__ inline f32x4 MFMA16(short8 a, short8 b, f32x4 c) {
  return mfma16_(a, b, c, 0);
}

__device__ inline void gload_lds16(const void* g, void* l) {
  __builtin_amdgcn_global_load_lds(
      (const __attribute__((address_space(1))) unsigned int*)g,
      (__attribute__((address_space(3))) unsigned int*)l, 16, 0, 0);
}

// ---- W -> bf16 (hi only), all three weights in one launch ----
__global__ __launch_bounds__(256) void conv_w(
    const float* __restrict__ Wq, const float* __restrict__ Wk,
    const float* __restrict__ Wv, ushort_t* __restrict__ Wh, int n4)
{
  int i = blockIdx.x * 256 + threadIdx.x;
  if (i >= n4) return;
  const float* src = (blockIdx.y == 0) ? Wq : ((blockIdx.y == 1) ? Wk : Wv);
  f32x4 x = ((const f32x4*)src)[i];
  us4 h;
  #pragma unroll
  for (int j = 0; j < 4; ++j) h[j] = f2bf(x[j]);
  ((us4*)(Wh + (size_t)blockIdx.y * DMODEL * DMODEL))[i] = h;
}

// ---- X -> bf16 hi + lo ----
__global__ __launch_bounds__(256) void split_x(
    const float* __restrict__ src, ushort_t* __restrict__ hi,
    ushort_t* __restrict__ lo, int n4)
{
  int i = blockIdx.x * 256 + threadIdx.x;
  if (i >= n4) return;
  f32x4 x = ((const f32x4*)src)[i];
  us4 h, l;
  #pragma unroll
  for (int j = 0; j < 4; ++j) {
    ushort_t hh = f2bf(x[j]);
    h[j] = hh;
    l[j] = f2bf(x[j] - bf2f(hh));
  }
  ((us4*)hi)[i] = h;
  ((us4*)lo)[i] = l;
}

// ---------------- GEMM: Y[z] = Xc @ W[z]^T, 2-term split ----------------
// 128x128 tile, BK=32, 256 threads (4 waves, 2x2, 64x64/wave), m97 pattern.
// (256,4): VGPR 60, no spill, 107us proven. Do NOT raise the min-wave bound.
__global__ __launch_bounds__(256, 4) void gemm2(
    const ushort_t* __restrict__ Xh, const ushort_t* __restrict__ Xl,
    const ushort_t* __restrict__ Wh, ushort_t* __restrict__ Y)
{
  __shared__ ushort_t Ah[128 * 32];  // 8 KB each, row-major stride 32
  __shared__ ushort_t Al[128 * 32];
  __shared__ ushort_t Bh[128 * 32];

  const int tid  = threadIdx.x;
  const int lane = tid & 63;
  const int wave = tid >> 6;
  const int quad = lane >> 4;
  const int l15  = lane & 15;
  const int wm   = wave & 1, wn = wave >> 1;

  const int m0 = blockIdx.x * 128;
  const int n0 = blockIdx.y * 128;
  const int z  = blockIdx.z;

  const ushort_t* Agh = Xh + (size_t)m0 * DMODEL;
  const ushort_t* Agl = Xl + (size_t)m0 * DMODEL;
  const ushort_t* Bgh = Wh + (size_t)z * DMODEL * DMODEL + (size_t)n0 * DMODEL;
  ushort_t* Yp = Y + (size_t)z * CHUNK * DMODEL;

  // staging: chunk c = p*256 + tid (16B = 8 bf16); row = c>>2, koff = (c&3)*8
  const int s_row = tid >> 2;
  const int s_off = (tid & 3) * 8;

  f32x4 acc[4][4] = {};

  const short8* Ahv = (const short8*)Ah;  // index = row*4 + k/8
  const short8* Alv = (const short8*)Al;
  const short8* Bhv = (const short8*)Bh;

  for (int k0 = 0; k0 < DMODEL; k0 += 32) {
    #pragma unroll
    for (int p = 0; p < 2; ++p) {
      size_t g = (size_t)(p * 64 + s_row) * DMODEL + k0 + s_off;
      int ldso = (p * 256 + wave * 64) * 16;
      gload_lds16(Agh + g, (char*)Ah + ldso);
      gload_lds16(Agl + g, (char*)Al + ldso);
      gload_lds16(Bgh + g, (char*)Bh + ldso);
    }
    __syncthreads();  // compiler drains vmcnt(0) before barrier

    short8 ah[4], al[4], bh[4];
    #pragma unroll
    for (int i = 0; i < 4; ++i) {
      int idx = (wm * 64 + i * 16 + l15) * 4 + quad;  // A[m=lane&15][k=quad*8+j]
      ah[i] = Ahv[idx];
      al[i] = Alv[idx];
    }
    #pragma unroll
    for (int j = 0; j < 4; ++j)
      bh[j] = Bhv[(wn * 64 + j * 16 + l15) * 4 + quad]; // B[k][n] = W[n][k]

    #pragma unroll
    for (int i = 0; i < 4; ++i) {
      #pragma unroll
      for (int j = 0; j < 4; ++j) {
        acc[i][j] = MFMA16(ah[i], bh[j], acc[i][j]);
        acc[i][j] = MFMA16(al[i], bh[j], acc[i][j]);
      }
    }
    __syncthreads();
  }

  // C/D layout: col = lane&15, row = quad*4 + reg
  #pragma unroll
  for (int i = 0; i < 4; ++i) {
    #pragma unroll
    for (int j = 0; j < 4; ++j) {
      #pragma unroll
      for (int r = 0; r < 4; ++r) {
        int row = m0 + wm * 64 + i * 16 + quad * 4 + r;
        int col = n0 + wn * 64 + j * 16 + l15;
        Yp[(size_t)row * DMODEL + col] = f2bf(acc[i][j][r]);
      }
    }
  }
}

// ---------------- Phase 2: per-token mixing (1 wave/token) ----------------
// out = (smQ . sK) . V ; M = smQ.sK is 16x16 -> 4x fewer LDS reads + FMAs
// than materializing tran_V (64x64).
__global__ __launch_bounds__(256) void attn_mix(
    const ushort_t* __restrict__ QKV, float* __restrict__ Out)
{
  // per-wave regions; stride 68 floats (272B, 16B-aligned, breaks bank stride)
  __shared__ float sqT_s[4][16 * 68];
  __shared__ float skT_s[4][16 * 68];
  __shared__ float M_s[4][256];

  const int tid  = threadIdx.x;
  const int lane = tid & 63;
  const int wv   = tid >> 6;
  const int tok  = blockIdx.x * 4 + wv;

  float* sqT = sqT_s[wv];
  float* skT = skT_s[wv];
  float* M   = M_s[wv];

  const size_t base = (size_t)tok * DMODEL;
  const ushort_t* Qg = QKV + base;
  const ushort_t* Kg = QKV + (size_t)CHUNK * DMODEL + base;
  const ushort_t* Vg = QKV + 2 * (size_t)CHUNK * DMODEL + base;

  float q[16], k[16], v[16];
  #pragma unroll
  for (int h = 0; h < 16; ++h) {
    q[h] = bf2f(Qg[h * 64 + lane]);
    k[h] = bf2f(Kg[h * 64 + lane]);
    v[h] = bf2f(Vg[h * 64 + lane]);
  }

  // sK[d=lane][h] = softmax over h of K[h][d]  (per-lane)
  float mx = k[0];
  #pragma unroll
  for (int h = 1; h < 16; ++h) mx = fmaxf(mx, k[h]);
  float ssum = 0.f;
  #pragma unroll
  for (int h = 0; h < 16; ++h) { k[h] = __expf(k[h] - mx); ssum += k[h]; }
  float inv = 1.f / ssum;
  #pragma unroll
  for (int h = 0; h < 16; ++h) skT[h * 68 + lane] = k[h] * inv;  // skT[h'][d]

  // smQ[h][d=lane] = softmax over d of Q[h][d]  (wave reductions)
  #pragma unroll
  for (int h = 0; h < 16; ++h) {
    float m = q[h];
    for (int off = 32; off; off >>= 1) m = fmaxf(m, __shfl_xor(m, off));
    float e = __expf(q[h] - m);
    float s2 = e;
    for (int off = 32; off; off >>= 1) s2 += __shfl_xor(s2, off);
    sqT[h * 68 + lane] = e / s2;                                 // sqT[h][d]
  }

  __syncthreads();

  // M[h][h'] = sum_d sqT[h][d] * skT[h'][d]; lane -> h=lane>>2, h'=(lane&3)*4+p
  {
    const int hm = lane >> 2;
    const int hp = (lane & 3) * 4;
    const f32x4* sqrow = (const f32x4*)(sqT + hm * 68);
    f32x4 m4;
    #pragma unroll
    for (int p = 0; p < 4; ++p) {
      const f32x4* skrow = (const f32x4*)(skT + (hp + p) * 68);
      float dot = 0.f;
      #pragma unroll
      for (int j = 0; j < 16; ++j) {
        f32x4 a = sqrow[j], b = skrow[j];
        dot += a[0] * b[0] + a[1] * b[1] + a[2] * b[2] + a[3] * b[3];
      }
      m4[p] = dot;
    }
    *((f32x4*)(M + hm * 16 + hp)) = m4;
  }

  __syncthreads();

  // out[h][e=lane] = sum_h' M[h][h'] * V[h'][e]  (M broadcast, v in regs)
  #pragma unroll
  for (int h = 0; h < 16; ++h) {
    const f32x4* mr = (const f32x4*)(M + h * 16);
    float o = 0.f;
    #pragma unroll
    for (int j = 0; j < 4; ++j) {
      f32x4 w = mr[j];
      o += w[0] * v[j * 4] + w[1] * v[j * 4 + 1] + w[2] * v[j * 4 + 2] + w[3] * v[j * 4 + 3];
    }
    Out[base + h * 64 + lane] = o;
  }
}

extern "C" void kernel_launch(void* const* d_in, const int* in_sizes, int n_in,
                              void* d_out, int out_size, void* d_ws, size_t ws_size,
                              hipStream_t stream) {
  const float* X  = (const float*)d_in[0];
  const float* Wq = (const float*)d_in[1];
  const float* Wk = (const float*)d_in[2];
  const float* Wv = (const float*)d_in[3];
  float* Out = (float*)d_out;

  // ws layout (ushort elems): Wh[3M] Xh[8M] Xl[8M] Y[24M] = 86 MB
  const size_t WSZ = (size_t)DMODEL * DMODEL;
  const size_t XSZ = (size_t)CHUNK * DMODEL;
  ushort_t* Wh = (ushort_t*)d_ws;
  ushort_t* Xh = Wh + 3 * WSZ;
  ushort_t* Xl = Xh + XSZ;
  ushort_t* Y  = Xl + XSZ;

  const int wn4 = (int)(WSZ / 4);
  dim3 gw((wn4 + 255) / 256, 3);
  conv_w<<<gw, 256, 0, stream>>>(Wq, Wk, Wv, Wh, wn4);

  const int xn4 = (int)(XSZ / 4);
  dim3 gg(CHUNK / 128, DMODEL / 128, 3);
  for (int c = 0; c < 2; ++c) {
    split_x<<<(xn4 + 255) / 256, 256, 0, stream>>>(X + (size_t)c * XSZ, Xh, Xl, xn4);
    gemm2<<<gg, 256, 0, stream>>>(Xh, Xl, Wh, Y);
    attn_mix<<<CHUNK / 4, 256, 0, stream>>>(Y, Out + (size_t)c * XSZ);
  }
}